// Round 18
// baseline (146.675 us; speedup 1.0000x reference)
//
#include <hip/hip_runtime.h>
#include <cstdint>
#include <cstddef>

#define B_   2
#define N_   65536
#define GXv  480
#define GYv  360
#define NHv  32
#define HWv  (GXv*GYv)          // 172800

typedef __attribute__((ext_vector_type(8))) short short8;
typedef __attribute__((ext_vector_type(8))) unsigned short ushort8;
typedef __attribute__((ext_vector_type(4))) float floatx4;

// round-to-nearest-even f32 -> bf16
__device__ __forceinline__ unsigned short f2bf(float f) {
    unsigned u = __float_as_uint(f);
    u += 0x7FFFu + ((u >> 16) & 1u);
    return (unsigned short)(u >> 16);
}
// packed bf16-pair -> order-preserving u16 keys (pos: u|0x8000, neg: ~u)
__device__ __forceinline__ unsigned bf2key2(unsigned d) {
    unsigned sgn = (d >> 15) & 0x00010001u;
    return d ^ (0x80008000u | (sgn * 0x7FFFu));
}
// inverse
__device__ __forceinline__ unsigned key2bf2(unsigned k) {
    unsigned sgn = (k >> 15) & 0x00010001u;      // 1 = originally positive
    return k ^ (0xFFFFFFFFu - sgn * 0x7FFFu);
}

// ---------------- init ----------------
__global__ void k_init_head(int* head) {
    int i = blockIdx.x * 256 + threadIdx.x;
    if (i < B_ * HWv) head[i] = -1;
}

// ---------------- voxel bucketing (linked lists) ----------------
// Chain order is atomic-nondeterministic, but max-pool is commutative and each
// voxel writes only its own output location -> output deterministic.
// (keep-cap MAX_PT=256 never triggers: 65536 pts over 129600 voxels.)
__global__ void k_chain(const int* __restrict__ xy, int* head, int* nxt) {
    int i = blockIdx.x * 256 + threadIdx.x;
    if (i >= B_ * N_) return;
    int b = i >> 16;
    int x = xy[2 * i], y = xy[2 * i + 1];
    nxt[i] = atomicExch(&head[b * HWv + x * GYv + y], i);
}

// ---------------- weight -> bf16 B-fragment-linear ----------------
// dst[((kc*NT + nt)*64 + l)*8 + j] = bf16(W[(kc*32 + (l>>4)*8 + j)*N + nt*16 + (l&15)])
__global__ void k_cvtB(const float* __restrict__ W, unsigned short* __restrict__ dst,
                       int K, int N) {
    int d = blockIdx.x * 256 + threadIdx.x;
    if (d >= (K * N) / 8) return;
    int l = d & 63;
    int g = d >> 6;
    int NT = N >> 4;
    int kc = g / NT, nt = g - kc * NT;
    int k0 = kc * 32 + (l >> 4) * 8, n = nt * 16 + (l & 15);
    __align__(16) unsigned short o[8];
    #pragma unroll
    for (int j = 0; j < 8; ++j) o[j] = f2bf(W[(size_t)(k0 + j) * N + n]);
    *reinterpret_cast<uint4*>(dst + (size_t)d * 8) = *reinterpret_cast<const uint4*>(o);
}

// ---------------- fused point MLP: A in LDS, B global->VGPR prefetch --------
// r17 base (77us) + T5 setprio around MFMA clusters + nh=1 single-pass 32KB
// rep (x3A dead after nh=1 kc loop). 48KB LDS, (256,3), 3 blocks/CU.
// x4 written in KEY form (bf2key2) for k_pool's packed-u16 max.
__global__ __launch_bounds__(256, 3) void k_mlp(
        const float* __restrict__ pt_fea,
        const float* __restrict__ s0v, const float* __restrict__ t0v,
        const float* __restrict__ s1v, const float* __restrict__ t1v,
        const float* __restrict__ s2v, const float* __restrict__ t2v,
        const float* __restrict__ s3v, const float* __restrict__ t3v,
        const float* __restrict__ W1, const float* __restrict__ b1,
        const unsigned short* __restrict__ W2B, const float* __restrict__ b2,
        const unsigned short* __restrict__ W3B, const float* __restrict__ b3,
        const unsigned short* __restrict__ W4B, const float* __restrict__ b4,
        unsigned short* __restrict__ x4out)
{
    __shared__ __align__(16) char smem[49152];
    unsigned short* x1A = (unsigned short*)smem;              // [0,8K)
    unsigned short* x3A = (unsigned short*)smem;              // [0,32K)
    unsigned short* x2A = (unsigned short*)(smem + 32768);    // [32K,48K)
    float*          x0s = (float*)(smem + 32768);             // [32K,+2.25K)
    unsigned short* rep = (unsigned short*)(smem + 32768);    // [32K,48K)
    unsigned short* rep32 = (unsigned short*)smem;            // [0,32K) nh=1 only

    const short8* W2v = reinterpret_cast<const short8*>(W2B);
    const short8* W3v = reinterpret_cast<const short8*>(W3B);
    const short8* W4v = reinterpret_cast<const short8*>(W4B);

    int tid = threadIdx.x;
    int w = tid >> 6, lane = tid & 63;
    int bid = blockIdx.x;                    // 2048 blocks
    int b = bid >> 10, n0 = (bid & 1023) << 6;
    const float* fea = pt_fea + ((size_t)(b * N_ + n0)) * 9;

    for (int idx = tid; idx < 576; idx += 256) {
        int kk = idx % 9;
        x0s[idx] = fea[idx] * s0v[kk] + t0v[kk];
    }
    short8 b2r[2][2];
    #pragma unroll
    for (int kc = 0; kc < 2; ++kc)
        #pragma unroll
        for (int t = 0; t < 2; ++t)
            b2r[kc][t] = W2v[(kc * 8 + w * 2 + t) * 64 + lane];
    __syncthreads();                         // x0 ready

    // ---- L1: 9->64 vector f32, writes x1A (A-frag bf16, KC=2) ----
    {
        int p = tid & 63, q = tid >> 6;
        float a0[9];
        #pragma unroll
        for (int k = 0; k < 9; ++k) a0[k] = x0s[p * 9 + k];
        float acc1[16];
        #pragma unroll
        for (int c = 0; c < 16; ++c) acc1[c] = 0.f;
        #pragma unroll
        for (int k = 0; k < 9; ++k) {
            #pragma unroll
            for (int c4 = 0; c4 < 4; ++c4) {
                float4 wv = *reinterpret_cast<const float4*>(&W1[k * 64 + q * 16 + c4 * 4]);
                acc1[c4*4+0] = fmaf(a0[k], wv.x, acc1[c4*4+0]);
                acc1[c4*4+1] = fmaf(a0[k], wv.y, acc1[c4*4+1]);
                acc1[c4*4+2] = fmaf(a0[k], wv.z, acc1[c4*4+2]);
                acc1[c4*4+3] = fmaf(a0[k], wv.w, acc1[c4*4+3]);
            }
        }
        #pragma unroll
        for (int h = 0; h < 2; ++h) {
            __align__(16) unsigned short o[8];
            #pragma unroll
            for (int j = 0; j < 8; ++j) {
                int c = q * 16 + h * 8 + j;
                o[j] = f2bf(fmaxf(fmaf(acc1[h * 8 + j] + b1[c], s1v[c], t1v[c]), 0.f));
            }
            int lane2 = (p & 15) + (((q & 1) * 2 + h) << 4);
            *reinterpret_cast<uint4*>(x1A + (((p >> 4) * 2 + (q >> 1)) * 64 + lane2) * 8) =
                *reinterpret_cast<const uint4*>(o);
        }
    }
    __syncthreads();                         // x1A visible

    // ---- L2: 64->128 MFMA, B in regs ----
    {
        floatx4 acc2[4][2];
        #pragma unroll
        for (int mt = 0; mt < 4; ++mt)
            #pragma unroll
            for (int nt = 0; nt < 2; ++nt) acc2[mt][nt] = (floatx4)0.f;
        __builtin_amdgcn_s_setprio(1);
        #pragma unroll
        for (int kc = 0; kc < 2; ++kc) {
            short8 a[4];
            #pragma unroll
            for (int mt = 0; mt < 4; ++mt)
                a[mt] = *reinterpret_cast<const short8*>(x1A + ((mt * 2 + kc) * 64 + lane) * 8);
            #pragma unroll
            for (int nt = 0; nt < 2; ++nt)
                #pragma unroll
                for (int mt = 0; mt < 4; ++mt)
                    acc2[mt][nt] = __builtin_amdgcn_mfma_f32_16x16x32_bf16(
                        a[mt], b2r[kc][nt], acc2[mt][nt], 0, 0, 0);
        }
        __builtin_amdgcn_s_setprio(0);
        #pragma unroll
        for (int nt = 0; nt < 2; ++nt) {
            int c = (w * 2 + nt) * 16 + (lane & 15);
            float bb = b2[c], sc = s2v[c], tt = t2v[c];
            #pragma unroll
            for (int mt = 0; mt < 4; ++mt)
                #pragma unroll
                for (int r = 0; r < 4; ++r) {
                    int ml = (lane >> 4) * 4 + r;
                    float v = fmaxf(fmaf(acc2[mt][nt][r] + bb, sc, tt), 0.f);
                    x2A[((mt * 4 + (c >> 5)) * 64 + ml + (((c >> 3) & 3) << 4)) * 8 + (c & 7)] = f2bf(v);
                }
        }
    }
    // prefetch L3 kc=0 and kc=1 B-frags (depth-2 ring)
    short8 bb3[3][4];
    #pragma unroll
    for (int t = 0; t < 4; ++t) bb3[0][t] = W3v[(w * 4 + t) * 64 + lane];
    #pragma unroll
    for (int t = 0; t < 4; ++t) bb3[1][t] = W3v[(16 + w * 4 + t) * 64 + lane];
    __syncthreads();                         // x2A visible

    // ---- L3: 128->256 MFMA, 4 kc, depth-2 B ring ----
    {
        floatx4 acc3[4][4];
        #pragma unroll
        for (int mt = 0; mt < 4; ++mt)
            #pragma unroll
            for (int nt = 0; nt < 4; ++nt) acc3[mt][nt] = (floatx4)0.f;
        __builtin_amdgcn_s_setprio(1);
        #pragma unroll
        for (int kc = 0; kc < 4; ++kc) {
            if (kc + 2 < 4) {
                #pragma unroll
                for (int t = 0; t < 4; ++t)
                    bb3[(kc + 2) % 3][t] = W3v[((kc + 2) * 16 + w * 4 + t) * 64 + lane];
            }
            short8 a[4];
            #pragma unroll
            for (int mt = 0; mt < 4; ++mt)
                a[mt] = *reinterpret_cast<const short8*>(x2A + ((mt * 4 + kc) * 64 + lane) * 8);
            #pragma unroll
            for (int nt = 0; nt < 4; ++nt)
                #pragma unroll
                for (int mt = 0; mt < 4; ++mt)
                    acc3[mt][nt] = __builtin_amdgcn_mfma_f32_16x16x32_bf16(
                        a[mt], bb3[kc % 3][nt], acc3[mt][nt], 0, 0, 0);
        }
        __builtin_amdgcn_s_setprio(0);
        #pragma unroll
        for (int nt = 0; nt < 4; ++nt) {
            int c = w * 64 + nt * 16 + (lane & 15);
            float bb = b3[c], sc = s3v[c], tt = t3v[c];
            #pragma unroll
            for (int mt = 0; mt < 4; ++mt)
                #pragma unroll
                for (int r = 0; r < 4; ++r) {
                    int ml = (lane >> 4) * 4 + r;
                    float v = fmaxf(fmaf(acc3[mt][nt][r] + bb, sc, tt), 0.f);
                    x3A[((mt * 8 + (c >> 5)) * 64 + ml + (((c >> 3) & 3) << 4)) * 8 + (c & 7)] = f2bf(v);
                }
        }
    }
    // prefetch L4 steps g=0,1 (nh0 kc0, nh0 kc1) into 3-slot ring
    short8 bb4[3][4];
    #pragma unroll
    for (int t = 0; t < 4; ++t) bb4[0][t] = W4v[(w * 4 + t) * 64 + lane];
    #pragma unroll
    for (int t = 0; t < 4; ++t) bb4[1][t] = W4v[(32 + w * 4 + t) * 64 + lane];
    __syncthreads();                         // x3A visible; all x2A reads done

    // ---- L4: 256->512 MFMA, 16 steps g=nh*8+kc, depth-2 B ring ----
    #pragma unroll
    for (int nh = 0; nh < 2; ++nh) {
        floatx4 acc4[4][4];
        #pragma unroll
        for (int mt = 0; mt < 4; ++mt)
            #pragma unroll
            for (int nt = 0; nt < 4; ++nt) acc4[mt][nt] = (floatx4)0.f;
        __builtin_amdgcn_s_setprio(1);
        #pragma unroll
        for (int kc = 0; kc < 8; ++kc) {
            const int g = nh * 8 + kc;
            if (g + 2 < 16) {
                const int g2 = g + 2, nh2 = g2 >> 3, kc2 = g2 & 7;
                #pragma unroll
                for (int t = 0; t < 4; ++t)
                    bb4[g2 % 3][t] = W4v[(kc2 * 32 + nh2 * 16 + w * 4 + t) * 64 + lane];
            }
            short8 a[4];
            #pragma unroll
            for (int mt = 0; mt < 4; ++mt)
                a[mt] = *reinterpret_cast<const short8*>(x3A + ((mt * 8 + kc) * 64 + lane) * 8);
            #pragma unroll
            for (int nt = 0; nt < 4; ++nt)
                #pragma unroll
                for (int mt = 0; mt < 4; ++mt)
                    acc4[mt][nt] = __builtin_amdgcn_mfma_f32_16x16x32_bf16(
                        a[mt], bb4[g % 3][nt], acc4[mt][nt], 0, 0, 0);
        }
        __builtin_amdgcn_s_setprio(0);
        unsigned short* orow = x4out + ((size_t)(b * N_ + n0)) * 512 + nh * 256;
        if (nh == 0) {
            // epilogue nh0: two 32-row halves through rep[32][256] (16KB)
            #pragma unroll
            for (int mh = 0; mh < 2; ++mh) {
                #pragma unroll
                for (int nt = 0; nt < 4; ++nt) {
                    int cl = w * 64 + nt * 16 + (lane & 15);
                    float bb = b4[cl];
                    #pragma unroll
                    for (int mt2 = 0; mt2 < 2; ++mt2) {
                        #pragma unroll
                        for (int r = 0; r < 4; ++r) {
                            int ml = mt2 * 16 + (lane >> 4) * 4 + r;
                            rep[ml * 256 + cl] = f2bf(acc4[mh * 2 + mt2][nt][r] + bb);
                        }
                    }
                }
                __syncthreads();             // rep half visible
                #pragma unroll
                for (int r2 = 0; r2 < 4; ++r2) {
                    int q = r2 * 256 + tid;  // uint4 index, 0..1023
                    int m = q >> 5, co = (q & 31) * 8;
                    uint4 v = *reinterpret_cast<const uint4*>(rep + m * 256 + co);
                    v.x = bf2key2(v.x); v.y = bf2key2(v.y);
                    v.z = bf2key2(v.z); v.w = bf2key2(v.w);
                    *reinterpret_cast<uint4*>(
                        &orow[((size_t)(mh * 32 + m)) * 512 + co]) = v;
                }
                __syncthreads();             // rep free for next half
            }
        } else {
            // epilogue nh1: x3A dead after this nh's MFMAs -> single-pass
            // 64-row rep32[64][256] in [0,32K)
            __syncthreads();                 // all waves' x3A reads done
            #pragma unroll
            for (int nt = 0; nt < 4; ++nt) {
                int cl = w * 64 + nt * 16 + (lane & 15);
                float bb = b4[256 + cl];
                #pragma unroll
                for (int mt = 0; mt < 4; ++mt)
                    #pragma unroll
                    for (int r = 0; r < 4; ++r) {
                        int m = mt * 16 + (lane >> 4) * 4 + r;
                        rep32[m * 256 + cl] = f2bf(acc4[mt][nt][r] + bb);
                    }
            }
            __syncthreads();                 // rep32 visible
            #pragma unroll
            for (int r2 = 0; r2 < 8; ++r2) {
                int q = r2 * 256 + tid;      // uint4 index, 0..2047
                int m = q >> 5, co = (q & 31) * 8;
                uint4 v = *reinterpret_cast<const uint4*>(rep32 + m * 256 + co);
                v.x = bf2key2(v.x); v.y = bf2key2(v.y);
                v.z = bf2key2(v.z); v.w = bf2key2(v.w);
                *reinterpret_cast<uint4*>(&orow[(size_t)m * 512 + co]) = v;
            }
        }
    }
}

// ---------------- per-voxel max-pool + MFMA compression, half-strip blocks --
// 1920 blocks: (b, x, half). x4 holds u16 KEYS: chain-walk max = v_pk_max_u16.
// mxA uses XOR swizzle dl ^= ((kc&3)<<2)|((dl>>4)&3) (conflict fix).
__global__ __launch_bounds__(256) void k_pool(
        const int* __restrict__ head, const int* __restrict__ nxt,
        const unsigned short* __restrict__ x4,
        const unsigned short* __restrict__ WcB, const float* __restrict__ bcv,
        float* __restrict__ out)
{
    __shared__ __align__(16) unsigned short mxA[16 * 64 * 8];  // 16KB, swizzled
    __shared__ float part[4][16 * 17];                          // stride-17 pad
    __shared__ int occ[16];
    int tid = threadIdx.x;
    int w = tid >> 6, lane = tid & 63;
    int kh = w >> 1, ntw = w & 1;
    int g = tid >> 4, l = tid & 15;          // phase-1: voxel slot, lane
    int s = blockIdx.x;                      // 1920 half-strips
    int half = s & 1, sx2 = s >> 1;
    int b = sx2 / GXv, x = sx2 - b * GXv;
    int ybase = half * 192;
    int ntiles = half ? 11 : 12;
    const int* hrow = head + (size_t)b * HWv + (size_t)x * GYv;

    // preload Wc B-fragments (iteration-invariant): 8 short8 = 32 VGPR
    short8 breg[8];
    #pragma unroll
    for (int kk = 0; kk < 8; ++kk)
        breg[kk] = *reinterpret_cast<const short8*>(
            WcB + (size_t)(((kh * 8 + kk) * 2 + ntw) * 64 + lane) * 8);

    #pragma unroll 1
    for (int t = 0; t < ntiles; ++t) {
        int y0 = ybase + t * 16;
        {   // ---- phase 1: chain walk, packed-key max, untransform + repack --
            int y = y0 + g;
            int h = (y < GYv) ? hrow[y] : -1;
            if (l == 0) occ[g] = h;
            ushort8 mx[4];
            if (h >= 0) {
                #pragma unroll
                for (int i = 0; i < 4; ++i) mx[i] = (ushort8)((unsigned short)0x007F); // key(-inf)
                int cur = h;
                while (cur >= 0) {
                    const ushort8* row = reinterpret_cast<const ushort8*>(x4 + (size_t)cur * 512);
                    ushort8 r0 = row[0 * 16 + l];
                    ushort8 r1 = row[1 * 16 + l];
                    ushort8 r2 = row[2 * 16 + l];
                    ushort8 r3 = row[3 * 16 + l];
                    mx[0] = __builtin_elementwise_max(mx[0], r0);
                    mx[1] = __builtin_elementwise_max(mx[1], r1);
                    mx[2] = __builtin_elementwise_max(mx[2], r2);
                    mx[3] = __builtin_elementwise_max(mx[3], r3);
                    cur = nxt[cur];
                }
            } else {
                #pragma unroll
                for (int i = 0; i < 4; ++i) mx[i] = (ushort8)((unsigned short)0x8000); // key(0)
            }
            // untransform keys -> bf16 and write A-frags (swizzled)
            #pragma unroll
            for (int i = 0; i < 4; ++i) {
                uint4 v = *reinterpret_cast<uint4*>(&mx[i]);
                v.x = key2bf2(v.x); v.y = key2bf2(v.y);
                v.z = key2bf2(v.z); v.w = key2bf2(v.w);
                int kc = i * 4 + (l >> 2);
                int dl = g | ((l & 3) << 4);
                int dls = dl ^ (((kc & 3) << 2) | ((dl >> 4) & 3));
                *reinterpret_cast<uint4*>(&mxA[(kc * 64 + dls) * 8]) = v;
            }
        }
        __syncthreads();
        {   // ---- phase 2: MFMA 16x32x512 (this wave: 8 k-chunks, 1 n-tile) --
            floatx4 acc = (floatx4)0.f;
            __builtin_amdgcn_s_setprio(1);
            #pragma unroll
            for (int kk = 0; kk < 8; ++kk) {
                int kk2 = kh * 8 + kk;
                int dls = lane ^ (((kk2 & 3) << 2) | ((lane >> 4) & 3));
                short8 a = *reinterpret_cast<const short8*>(&mxA[(kk2 * 64 + dls) * 8]);
                acc = __builtin_amdgcn_mfma_f32_16x16x32_bf16(a, breg[kk], acc, 0, 0, 0);
            }
            __builtin_amdgcn_s_setprio(0);
            #pragma unroll
            for (int r = 0; r < 4; ++r)
                part[w][((lane >> 4) * 4 + r) * 17 + (lane & 15)] = acc[r];
        }
        __syncthreads();
        {   // ---- phase 2b: K-reduce + bias + relu + COALESCED strip write ----
            int m = tid & 15, n = tid >> 4;          // voxel m, channel n / n+16
            int y = y0 + m;
            if (y < GYv) {
                bool o = occ[m] >= 0;
                float v0 = o ? fmaxf(part[0][m * 17 + n] + part[2][m * 17 + n] + bcv[n], 0.f) : 0.f;
                float v1 = o ? fmaxf(part[1][m * 17 + n] + part[3][m * 17 + n] + bcv[n + 16], 0.f) : 0.f;
                out[(((size_t)b * NHv + n)      * GXv + x) * GYv + y] = v0;
                out[(((size_t)b * NHv + n + 16) * GXv + x) * GYv + y] = v1;
            }
        }
        __syncthreads();                             // protect occ/mxA/part
    }
}

extern "C" void kernel_launch(void* const* d_in, const int* in_sizes, int n_in,
                              void* d_out, int out_size, void* d_ws, size_t ws_size,
                              hipStream_t stream) {
    const float* pt_fea = (const float*)d_in[0];
    const int*   xy     = (const int*)d_in[1];
    const float* s0v = (const float*)d_in[2];  const float* t0v = (const float*)d_in[3];
    const float* s1v = (const float*)d_in[4];  const float* t1v = (const float*)d_in[5];
    const float* s2v = (const float*)d_in[6];  const float* t2v = (const float*)d_in[7];
    const float* s3v = (const float*)d_in[8];  const float* t3v = (const float*)d_in[9];
    const float* W1  = (const float*)d_in[10]; const float* b1  = (const float*)d_in[11];
    const float* W2  = (const float*)d_in[12]; const float* b2  = (const float*)d_in[13];
    const float* W3  = (const float*)d_in[14]; const float* b3  = (const float*)d_in[15];
    const float* W4  = (const float*)d_in[16]; const float* b4  = (const float*)d_in[17];
    const float* Wc  = (const float*)d_in[18]; const float* bc  = (const float*)d_in[19];

    // workspace: x4 | head | nxt | W2B | W3B | W4B | WcB
    char* ws = (char*)d_ws;
    size_t off = 0;
    unsigned short* x4   = (unsigned short*)(ws + off); off += (size_t)B_ * N_ * 512 * 2;
    int* head            = (int*)(ws + off);            off += (size_t)B_ * HWv * 4;
    int* nxt             = (int*)(ws + off);            off += (size_t)B_ * N_ * 4;
    unsigned short* W2B  = (unsigned short*)(ws + off); off += 64 * 128 * 2;
    unsigned short* W3B  = (unsigned short*)(ws + off); off += 128 * 256 * 2;
    unsigned short* W4B  = (unsigned short*)(ws + off); off += 256 * 512 * 2;
    unsigned short* WcB  = (unsigned short*)(ws + off); off += 512 * 32 * 2;

    hipLaunchKernelGGL(k_init_head, dim3(1350), dim3(256), 0, stream, head);
    hipLaunchKernelGGL(k_chain,     dim3(512),  dim3(256), 0, stream, xy, head, nxt);
    hipLaunchKernelGGL(k_cvtB,      dim3(4),    dim3(256), 0, stream, W2, W2B, 64, 128);
    hipLaunchKernelGGL(k_cvtB,      dim3(16),   dim3(256), 0, stream, W3, W3B, 128, 256);
    hipLaunchKernelGGL(k_cvtB,      dim3(64),   dim3(256), 0, stream, W4, W4B, 256, 512);
    hipLaunchKernelGGL(k_cvtB,      dim3(8),    dim3(256), 0, stream, Wc, WcB, 512, 32);
    hipLaunchKernelGGL(k_mlp,       dim3(2048), dim3(256), 0, stream,
        pt_fea, s0v, t0v, s1v, t1v, s2v, t2v, s3v, t3v,
        W1, b1, W2B, b2, W3B, b3, W4B, b4, x4);
    hipLaunchKernelGGL(k_pool,      dim3(1920), dim3(256), 0, stream,
        head, nxt, x4, WcB, bc, (float*)d_out);
}

// Round 19
// 138.943 us; speedup vs baseline: 1.0556x; 1.0556x over previous
//
#include <hip/hip_runtime.h>
#include <cstdint>
#include <cstddef>

#define B_   2
#define N_   65536
#define GXv  480
#define GYv  360
#define NHv  32
#define HWv  (GXv*GYv)          // 172800

typedef __attribute__((ext_vector_type(8))) short short8;
typedef __attribute__((ext_vector_type(8))) unsigned short ushort8;
typedef __attribute__((ext_vector_type(4))) float floatx4;

// round-to-nearest-even f32 -> bf16
__device__ __forceinline__ unsigned short f2bf(float f) {
    unsigned u = __float_as_uint(f);
    u += 0x7FFFu + ((u >> 16) & 1u);
    return (unsigned short)(u >> 16);
}
// packed bf16-pair -> order-preserving u16 keys (pos: u|0x8000, neg: ~u)
__device__ __forceinline__ unsigned bf2key2(unsigned d) {
    unsigned sgn = (d >> 15) & 0x00010001u;
    return d ^ (0x80008000u | (sgn * 0x7FFFu));
}
// inverse
__device__ __forceinline__ unsigned key2bf2(unsigned k) {
    unsigned sgn = (k >> 15) & 0x00010001u;      // 1 = originally positive
    return k ^ (0xFFFFFFFFu - sgn * 0x7FFFu);
}

// weight -> bf16 B-fragment-linear (device helper)
// dst[((kc*NT + nt)*64 + l)*8 + j] = bf16(W[(kc*32 + (l>>4)*8 + j)*N + nt*16 + (l&15)])
__device__ __forceinline__ void cvtB_block(const float* __restrict__ W,
        unsigned short* __restrict__ dst, int K, int N, int blk, int tid) {
    int d = blk * 256 + tid;
    if (d >= (K * N) / 8) return;
    int l = d & 63;
    int g = d >> 6;
    int NT = N >> 4;
    int kc = g / NT, nt = g - kc * NT;
    int k0 = kc * 32 + (l >> 4) * 8, n = nt * 16 + (l & 15);
    __align__(16) unsigned short o[8];
    #pragma unroll
    for (int j = 0; j < 8; ++j) o[j] = f2bf(W[(size_t)(k0 + j) * N + n]);
    *reinterpret_cast<uint4*>(dst + (size_t)d * 8) = *reinterpret_cast<const uint4*>(o);
}

// ---------------- fused setup: head init + all weight conversions ----------
// blocks [0,1350): head=-1 ; [1350,1354): W2 ; [1354,1370): W3 ;
// [1370,1434): W4 ; [1434,1442): Wc
__global__ void k_setup(int* head,
        const float* __restrict__ W2, unsigned short* __restrict__ W2B,
        const float* __restrict__ W3, unsigned short* __restrict__ W3B,
        const float* __restrict__ W4, unsigned short* __restrict__ W4B,
        const float* __restrict__ Wc, unsigned short* __restrict__ WcB) {
    int blk = blockIdx.x, tid = threadIdx.x;
    if (blk < 1350) {
        int i = blk * 256 + tid;
        if (i < B_ * HWv) head[i] = -1;
    } else if (blk < 1354) {
        cvtB_block(W2, W2B, 64, 128, blk - 1350, tid);
    } else if (blk < 1370) {
        cvtB_block(W3, W3B, 128, 256, blk - 1354, tid);
    } else if (blk < 1434) {
        cvtB_block(W4, W4B, 256, 512, blk - 1370, tid);
    } else {
        cvtB_block(Wc, WcB, 512, 32, blk - 1434, tid);
    }
}

// ---------------- voxel bucketing (linked lists) ----------------
// Chain order is atomic-nondeterministic, but max-pool is commutative and each
// voxel writes only its own output location -> output deterministic.
// (keep-cap MAX_PT=256 never triggers: 65536 pts over 129600 voxels.)
__global__ void k_chain(const int* __restrict__ xy, int* head, int* nxt) {
    int i = blockIdx.x * 256 + threadIdx.x;
    if (i >= B_ * N_) return;
    int b = i >> 16;
    int x = xy[2 * i], y = xy[2 * i + 1];
    nxt[i] = atomicExch(&head[b * HWv + x * GYv + y], i);
}

// ---------------- fused point MLP: A in LDS, B global->VGPR prefetch --------
// r17 structure (77us): depth-2 B rings, T5 setprio, nh1 single-pass rep32.
// 48KB LDS, (256,3), 3 blocks/CU. x4 written in KEY form (bf2key2).
__global__ __launch_bounds__(256, 3) void k_mlp(
        const float* __restrict__ pt_fea,
        const float* __restrict__ s0v, const float* __restrict__ t0v,
        const float* __restrict__ s1v, const float* __restrict__ t1v,
        const float* __restrict__ s2v, const float* __restrict__ t2v,
        const float* __restrict__ s3v, const float* __restrict__ t3v,
        const float* __restrict__ W1, const float* __restrict__ b1,
        const unsigned short* __restrict__ W2B, const float* __restrict__ b2,
        const unsigned short* __restrict__ W3B, const float* __restrict__ b3,
        const unsigned short* __restrict__ W4B, const float* __restrict__ b4,
        unsigned short* __restrict__ x4out)
{
    __shared__ __align__(16) char smem[49152];
    unsigned short* x1A = (unsigned short*)smem;              // [0,8K)
    unsigned short* x3A = (unsigned short*)smem;              // [0,32K)
    unsigned short* x2A = (unsigned short*)(smem + 32768);    // [32K,48K)
    float*          x0s = (float*)(smem + 32768);             // [32K,+2.25K)
    unsigned short* rep = (unsigned short*)(smem + 32768);    // [32K,48K)
    unsigned short* rep32 = (unsigned short*)smem;            // [0,32K) nh=1 only

    const short8* W2v = reinterpret_cast<const short8*>(W2B);
    const short8* W3v = reinterpret_cast<const short8*>(W3B);
    const short8* W4v = reinterpret_cast<const short8*>(W4B);

    int tid = threadIdx.x;
    int w = tid >> 6, lane = tid & 63;
    int bid = blockIdx.x;                    // 2048 blocks
    int b = bid >> 10, n0 = (bid & 1023) << 6;
    const float* fea = pt_fea + ((size_t)(b * N_ + n0)) * 9;

    for (int idx = tid; idx < 576; idx += 256) {
        int kk = idx % 9;
        x0s[idx] = fea[idx] * s0v[kk] + t0v[kk];
    }
    short8 b2r[2][2];
    #pragma unroll
    for (int kc = 0; kc < 2; ++kc)
        #pragma unroll
        for (int t = 0; t < 2; ++t)
            b2r[kc][t] = W2v[(kc * 8 + w * 2 + t) * 64 + lane];
    __syncthreads();                         // x0 ready

    // ---- L1: 9->64 vector f32, writes x1A (A-frag bf16, KC=2) ----
    {
        int p = tid & 63, q = tid >> 6;
        float a0[9];
        #pragma unroll
        for (int k = 0; k < 9; ++k) a0[k] = x0s[p * 9 + k];
        float acc1[16];
        #pragma unroll
        for (int c = 0; c < 16; ++c) acc1[c] = 0.f;
        #pragma unroll
        for (int k = 0; k < 9; ++k) {
            #pragma unroll
            for (int c4 = 0; c4 < 4; ++c4) {
                float4 wv = *reinterpret_cast<const float4*>(&W1[k * 64 + q * 16 + c4 * 4]);
                acc1[c4*4+0] = fmaf(a0[k], wv.x, acc1[c4*4+0]);
                acc1[c4*4+1] = fmaf(a0[k], wv.y, acc1[c4*4+1]);
                acc1[c4*4+2] = fmaf(a0[k], wv.z, acc1[c4*4+2]);
                acc1[c4*4+3] = fmaf(a0[k], wv.w, acc1[c4*4+3]);
            }
        }
        #pragma unroll
        for (int h = 0; h < 2; ++h) {
            __align__(16) unsigned short o[8];
            #pragma unroll
            for (int j = 0; j < 8; ++j) {
                int c = q * 16 + h * 8 + j;
                o[j] = f2bf(fmaxf(fmaf(acc1[h * 8 + j] + b1[c], s1v[c], t1v[c]), 0.f));
            }
            int lane2 = (p & 15) + (((q & 1) * 2 + h) << 4);
            *reinterpret_cast<uint4*>(x1A + (((p >> 4) * 2 + (q >> 1)) * 64 + lane2) * 8) =
                *reinterpret_cast<const uint4*>(o);
        }
    }
    __syncthreads();                         // x1A visible

    // ---- L2: 64->128 MFMA, B in regs ----
    {
        floatx4 acc2[4][2];
        #pragma unroll
        for (int mt = 0; mt < 4; ++mt)
            #pragma unroll
            for (int nt = 0; nt < 2; ++nt) acc2[mt][nt] = (floatx4)0.f;
        __builtin_amdgcn_s_setprio(1);
        #pragma unroll
        for (int kc = 0; kc < 2; ++kc) {
            short8 a[4];
            #pragma unroll
            for (int mt = 0; mt < 4; ++mt)
                a[mt] = *reinterpret_cast<const short8*>(x1A + ((mt * 2 + kc) * 64 + lane) * 8);
            #pragma unroll
            for (int nt = 0; nt < 2; ++nt)
                #pragma unroll
                for (int mt = 0; mt < 4; ++mt)
                    acc2[mt][nt] = __builtin_amdgcn_mfma_f32_16x16x32_bf16(
                        a[mt], b2r[kc][nt], acc2[mt][nt], 0, 0, 0);
        }
        __builtin_amdgcn_s_setprio(0);
        #pragma unroll
        for (int nt = 0; nt < 2; ++nt) {
            int c = (w * 2 + nt) * 16 + (lane & 15);
            float bb = b2[c], sc = s2v[c], tt = t2v[c];
            #pragma unroll
            for (int mt = 0; mt < 4; ++mt)
                #pragma unroll
                for (int r = 0; r < 4; ++r) {
                    int ml = (lane >> 4) * 4 + r;
                    float v = fmaxf(fmaf(acc2[mt][nt][r] + bb, sc, tt), 0.f);
                    x2A[((mt * 4 + (c >> 5)) * 64 + ml + (((c >> 3) & 3) << 4)) * 8 + (c & 7)] = f2bf(v);
                }
        }
    }
    // prefetch L3 kc=0 and kc=1 B-frags (depth-2 ring)
    short8 bb3[3][4];
    #pragma unroll
    for (int t = 0; t < 4; ++t) bb3[0][t] = W3v[(w * 4 + t) * 64 + lane];
    #pragma unroll
    for (int t = 0; t < 4; ++t) bb3[1][t] = W3v[(16 + w * 4 + t) * 64 + lane];
    __syncthreads();                         // x2A visible

    // ---- L3: 128->256 MFMA, 4 kc, depth-2 B ring ----
    {
        floatx4 acc3[4][4];
        #pragma unroll
        for (int mt = 0; mt < 4; ++mt)
            #pragma unroll
            for (int nt = 0; nt < 4; ++nt) acc3[mt][nt] = (floatx4)0.f;
        __builtin_amdgcn_s_setprio(1);
        #pragma unroll
        for (int kc = 0; kc < 4; ++kc) {
            if (kc + 2 < 4) {
                #pragma unroll
                for (int t = 0; t < 4; ++t)
                    bb3[(kc + 2) % 3][t] = W3v[((kc + 2) * 16 + w * 4 + t) * 64 + lane];
            }
            short8 a[4];
            #pragma unroll
            for (int mt = 0; mt < 4; ++mt)
                a[mt] = *reinterpret_cast<const short8*>(x2A + ((mt * 4 + kc) * 64 + lane) * 8);
            #pragma unroll
            for (int nt = 0; nt < 4; ++nt)
                #pragma unroll
                for (int mt = 0; mt < 4; ++mt)
                    acc3[mt][nt] = __builtin_amdgcn_mfma_f32_16x16x32_bf16(
                        a[mt], bb3[kc % 3][nt], acc3[mt][nt], 0, 0, 0);
        }
        __builtin_amdgcn_s_setprio(0);
        #pragma unroll
        for (int nt = 0; nt < 4; ++nt) {
            int c = w * 64 + nt * 16 + (lane & 15);
            float bb = b3[c], sc = s3v[c], tt = t3v[c];
            #pragma unroll
            for (int mt = 0; mt < 4; ++mt)
                #pragma unroll
                for (int r = 0; r < 4; ++r) {
                    int ml = (lane >> 4) * 4 + r;
                    float v = fmaxf(fmaf(acc3[mt][nt][r] + bb, sc, tt), 0.f);
                    x3A[((mt * 8 + (c >> 5)) * 64 + ml + (((c >> 3) & 3) << 4)) * 8 + (c & 7)] = f2bf(v);
                }
        }
    }
    // prefetch L4 steps g=0,1 (nh0 kc0, nh0 kc1) into 3-slot ring
    short8 bb4[3][4];
    #pragma unroll
    for (int t = 0; t < 4; ++t) bb4[0][t] = W4v[(w * 4 + t) * 64 + lane];
    #pragma unroll
    for (int t = 0; t < 4; ++t) bb4[1][t] = W4v[(32 + w * 4 + t) * 64 + lane];
    __syncthreads();                         // x3A visible; all x2A reads done

    // ---- L4: 256->512 MFMA, 16 steps g=nh*8+kc, depth-2 B ring ----
    #pragma unroll
    for (int nh = 0; nh < 2; ++nh) {
        floatx4 acc4[4][4];
        #pragma unroll
        for (int mt = 0; mt < 4; ++mt)
            #pragma unroll
            for (int nt = 0; nt < 4; ++nt) acc4[mt][nt] = (floatx4)0.f;
        __builtin_amdgcn_s_setprio(1);
        #pragma unroll
        for (int kc = 0; kc < 8; ++kc) {
            const int g = nh * 8 + kc;
            if (g + 2 < 16) {
                const int g2 = g + 2, nh2 = g2 >> 3, kc2 = g2 & 7;
                #pragma unroll
                for (int t = 0; t < 4; ++t)
                    bb4[g2 % 3][t] = W4v[(kc2 * 32 + nh2 * 16 + w * 4 + t) * 64 + lane];
            }
            short8 a[4];
            #pragma unroll
            for (int mt = 0; mt < 4; ++mt)
                a[mt] = *reinterpret_cast<const short8*>(x3A + ((mt * 8 + kc) * 64 + lane) * 8);
            #pragma unroll
            for (int nt = 0; nt < 4; ++nt)
                #pragma unroll
                for (int mt = 0; mt < 4; ++mt)
                    acc4[mt][nt] = __builtin_amdgcn_mfma_f32_16x16x32_bf16(
                        a[mt], bb4[g % 3][nt], acc4[mt][nt], 0, 0, 0);
        }
        __builtin_amdgcn_s_setprio(0);
        unsigned short* orow = x4out + ((size_t)(b * N_ + n0)) * 512 + nh * 256;
        if (nh == 0) {
            // epilogue nh0: two 32-row halves through rep[32][256] (16KB)
            #pragma unroll
            for (int mh = 0; mh < 2; ++mh) {
                #pragma unroll
                for (int nt = 0; nt < 4; ++nt) {
                    int cl = w * 64 + nt * 16 + (lane & 15);
                    float bb = b4[cl];
                    #pragma unroll
                    for (int mt2 = 0; mt2 < 2; ++mt2) {
                        #pragma unroll
                        for (int r = 0; r < 4; ++r) {
                            int ml = mt2 * 16 + (lane >> 4) * 4 + r;
                            rep[ml * 256 + cl] = f2bf(acc4[mh * 2 + mt2][nt][r] + bb);
                        }
                    }
                }
                __syncthreads();             // rep half visible
                #pragma unroll
                for (int r2 = 0; r2 < 4; ++r2) {
                    int q = r2 * 256 + tid;  // uint4 index, 0..1023
                    int m = q >> 5, co = (q & 31) * 8;
                    uint4 v = *reinterpret_cast<const uint4*>(rep + m * 256 + co);
                    v.x = bf2key2(v.x); v.y = bf2key2(v.y);
                    v.z = bf2key2(v.z); v.w = bf2key2(v.w);
                    *reinterpret_cast<uint4*>(
                        &orow[((size_t)(mh * 32 + m)) * 512 + co]) = v;
                }
                __syncthreads();             // rep free for next half
            }
        } else {
            // epilogue nh1: x3A dead -> single-pass 64-row rep32[64][256]
            __syncthreads();                 // all waves' x3A reads done
            #pragma unroll
            for (int nt = 0; nt < 4; ++nt) {
                int cl = w * 64 + nt * 16 + (lane & 15);
                float bb = b4[256 + cl];
                #pragma unroll
                for (int mt = 0; mt < 4; ++mt)
                    #pragma unroll
                    for (int r = 0; r < 4; ++r) {
                        int m = mt * 16 + (lane >> 4) * 4 + r;
                        rep32[m * 256 + cl] = f2bf(acc4[mt][nt][r] + bb);
                    }
            }
            __syncthreads();                 // rep32 visible
            #pragma unroll
            for (int r2 = 0; r2 < 8; ++r2) {
                int q = r2 * 256 + tid;      // uint4 index, 0..2047
                int m = q >> 5, co = (q & 31) * 8;
                uint4 v = *reinterpret_cast<const uint4*>(rep32 + m * 256 + co);
                v.x = bf2key2(v.x); v.y = bf2key2(v.y);
                v.z = bf2key2(v.z); v.w = bf2key2(v.w);
                *reinterpret_cast<uint4*>(&orow[(size_t)m * 512 + co]) = v;
            }
        }
    }
}

// ---------------- per-voxel max-pool + MFMA compression, half-strip blocks --
// 1920 blocks: (b, x, half). x4 holds u16 KEYS: chain-walk max = v_pk_max_u16.
// mxA uses XOR swizzle dl ^= ((kc&3)<<2)|((dl>>4)&3) (conflict fix).
__global__ __launch_bounds__(256) void k_pool(
        const int* __restrict__ head, const int* __restrict__ nxt,
        const unsigned short* __restrict__ x4,
        const unsigned short* __restrict__ WcB, const float* __restrict__ bcv,
        float* __restrict__ out)
{
    __shared__ __align__(16) unsigned short mxA[16 * 64 * 8];  // 16KB, swizzled
    __shared__ float part[4][16 * 17];                          // stride-17 pad
    __shared__ int occ[16];
    int tid = threadIdx.x;
    int w = tid >> 6, lane = tid & 63;
    int kh = w >> 1, ntw = w & 1;
    int g = tid >> 4, l = tid & 15;          // phase-1: voxel slot, lane
    int s = blockIdx.x;                      // 1920 half-strips
    int half = s & 1, sx2 = s >> 1;
    int b = sx2 / GXv, x = sx2 - b * GXv;
    int ybase = half * 192;
    int ntiles = half ? 11 : 12;
    const int* hrow = head + (size_t)b * HWv + (size_t)x * GYv;

    // preload Wc B-fragments (iteration-invariant): 8 short8 = 32 VGPR
    short8 breg[8];
    #pragma unroll
    for (int kk = 0; kk < 8; ++kk)
        breg[kk] = *reinterpret_cast<const short8*>(
            WcB + (size_t)(((kh * 8 + kk) * 2 + ntw) * 64 + lane) * 8);

    #pragma unroll 1
    for (int t = 0; t < ntiles; ++t) {
        int y0 = ybase + t * 16;
        {   // ---- phase 1: chain walk, packed-key max, untransform + repack --
            int y = y0 + g;
            int h = (y < GYv) ? hrow[y] : -1;
            if (l == 0) occ[g] = h;
            ushort8 mx[4];
            if (h >= 0) {
                #pragma unroll
                for (int i = 0; i < 4; ++i) mx[i] = (ushort8)((unsigned short)0x007F); // key(-inf)
                int cur = h;
                while (cur >= 0) {
                    const ushort8* row = reinterpret_cast<const ushort8*>(x4 + (size_t)cur * 512);
                    ushort8 r0 = row[0 * 16 + l];
                    ushort8 r1 = row[1 * 16 + l];
                    ushort8 r2 = row[2 * 16 + l];
                    ushort8 r3 = row[3 * 16 + l];
                    mx[0] = __builtin_elementwise_max(mx[0], r0);
                    mx[1] = __builtin_elementwise_max(mx[1], r1);
                    mx[2] = __builtin_elementwise_max(mx[2], r2);
                    mx[3] = __builtin_elementwise_max(mx[3], r3);
                    cur = nxt[cur];
                }
            } else {
                #pragma unroll
                for (int i = 0; i < 4; ++i) mx[i] = (ushort8)((unsigned short)0x8000); // key(0)
            }
            // untransform keys -> bf16 and write A-frags (swizzled)
            #pragma unroll
            for (int i = 0; i < 4; ++i) {
                uint4 v = *reinterpret_cast<uint4*>(&mx[i]);
                v.x = key2bf2(v.x); v.y = key2bf2(v.y);
                v.z = key2bf2(v.z); v.w = key2bf2(v.w);
                int kc = i * 4 + (l >> 2);
                int dl = g | ((l & 3) << 4);
                int dls = dl ^ (((kc & 3) << 2) | ((dl >> 4) & 3));
                *reinterpret_cast<uint4*>(&mxA[(kc * 64 + dls) * 8]) = v;
            }
        }
        __syncthreads();
        {   // ---- phase 2: MFMA 16x32x512 (this wave: 8 k-chunks, 1 n-tile) --
            floatx4 acc = (floatx4)0.f;
            __builtin_amdgcn_s_setprio(1);
            #pragma unroll
            for (int kk = 0; kk < 8; ++kk) {
                int kk2 = kh * 8 + kk;
                int dls = lane ^ (((kk2 & 3) << 2) | ((lane >> 4) & 3));
                short8 a = *reinterpret_cast<const short8*>(&mxA[(kk2 * 64 + dls) * 8]);
                acc = __builtin_amdgcn_mfma_f32_16x16x32_bf16(a, breg[kk], acc, 0, 0, 0);
            }
            __builtin_amdgcn_s_setprio(0);
            #pragma unroll
            for (int r = 0; r < 4; ++r)
                part[w][((lane >> 4) * 4 + r) * 17 + (lane & 15)] = acc[r];
        }
        __syncthreads();
        {   // ---- phase 2b: K-reduce + bias + relu + COALESCED strip write ----
            int m = tid & 15, n = tid >> 4;          // voxel m, channel n / n+16
            int y = y0 + m;
            if (y < GYv) {
                bool o = occ[m] >= 0;
                float v0 = o ? fmaxf(part[0][m * 17 + n] + part[2][m * 17 + n] + bcv[n], 0.f) : 0.f;
                float v1 = o ? fmaxf(part[1][m * 17 + n] + part[3][m * 17 + n] + bcv[n + 16], 0.f) : 0.f;
                out[(((size_t)b * NHv + n)      * GXv + x) * GYv + y] = v0;
                out[(((size_t)b * NHv + n + 16) * GXv + x) * GYv + y] = v1;
            }
        }
        __syncthreads();                             // protect occ/mxA/part
    }
}

extern "C" void kernel_launch(void* const* d_in, const int* in_sizes, int n_in,
                              void* d_out, int out_size, void* d_ws, size_t ws_size,
                              hipStream_t stream) {
    const float* pt_fea = (const float*)d_in[0];
    const int*   xy     = (const int*)d_in[1];
    const float* s0v = (const float*)d_in[2];  const float* t0v = (const float*)d_in[3];
    const float* s1v = (const float*)d_in[4];  const float* t1v = (const float*)d_in[5];
    const float* s2v = (const float*)d_in[6];  const float* t2v = (const float*)d_in[7];
    const float* s3v = (const float*)d_in[8];  const float* t3v = (const float*)d_in[9];
    const float* W1  = (const float*)d_in[10]; const float* b1  = (const float*)d_in[11];
    const float* W2  = (const float*)d_in[12]; const float* b2  = (const float*)d_in[13];
    const float* W3  = (const float*)d_in[14]; const float* b3  = (const float*)d_in[15];
    const float* W4  = (const float*)d_in[16]; const float* b4  = (const float*)d_in[17];
    const float* Wc  = (const float*)d_in[18]; const float* bc  = (const float*)d_in[19];

    // workspace: x4 | head | nxt | W2B | W3B | W4B | WcB
    char* ws = (char*)d_ws;
    size_t off = 0;
    unsigned short* x4   = (unsigned short*)(ws + off); off += (size_t)B_ * N_ * 512 * 2;
    int* head            = (int*)(ws + off);            off += (size_t)B_ * HWv * 4;
    int* nxt             = (int*)(ws + off);            off += (size_t)B_ * N_ * 4;
    unsigned short* W2B  = (unsigned short*)(ws + off); off += 64 * 128 * 2;
    unsigned short* W3B  = (unsigned short*)(ws + off); off += 128 * 256 * 2;
    unsigned short* W4B  = (unsigned short*)(ws + off); off += 256 * 512 * 2;
    unsigned short* WcB  = (unsigned short*)(ws + off); off += 512 * 32 * 2;

    hipLaunchKernelGGL(k_setup, dim3(1442), dim3(256), 0, stream,
        head, W2, W2B, W3, W3B, W4, W4B, Wc, WcB);
    hipLaunchKernelGGL(k_chain, dim3(512),  dim3(256), 0, stream, xy, head, nxt);
    hipLaunchKernelGGL(k_mlp,   dim3(2048), dim3(256), 0, stream,
        pt_fea, s0v, t0v, s1v, t1v, s2v, t2v, s3v, t3v,
        W1, b1, W2B, b2, W3B, b3, W4B, b4, x4);
    hipLaunchKernelGGL(k_pool,  dim3(1920), dim3(256), 0, stream,
        head, nxt, x4, WcB, bc, (float*)d_out);
}